// Round 1
// baseline (566.134 us; speedup 1.0000x reference)
//
#include <hip/hip_runtime.h>

#define B_  4
#define S_  4096
#define DH  1024
#define DL  256
#define KK  64
#define KH  4
#define WW  9

// ---------------------------------------------------------------------------
// Tiled fp32 GEMM: C[M x N] = op(A[M x KA] @ Bm[KA x N] (+bias, relu))
// GATHER: A row for column-block i (= k/256) comes from q[gidx[m*KH+i], :]
// TRANSOUT: store C transposed per batch as [b][n][s] (for RMVsT)
// BM=BN=64, BK=16, 256 threads, 4x4 micro-tile per thread.
// ---------------------------------------------------------------------------
template<bool GATHER, bool FUSE, bool TRANSOUT>
__global__ __launch_bounds__(256)
void gemm_kernel(const float* __restrict__ A, const float* __restrict__ Bm,
                 const float* __restrict__ bias, float* __restrict__ C,
                 const int* __restrict__ gidx, int M, int KA, int N)
{
    constexpr int BM = 64, BN = 64, BK = 16;
    __shared__ float As[BK][BM + 4];
    __shared__ float Bs[BK][BN + 4];
    const int tid = threadIdx.x;
    const int tx = tid & 15, ty = tid >> 4;
    const int m0 = blockIdx.y * BM, n0 = blockIdx.x * BN;

    float acc[4][4] = {};

    const int lr = tid >> 2;          // A-load row within tile: 0..63
    const int lc = (tid & 3) << 2;    // A-load col: 0,4,8,12
    const int kr = tid >> 4;          // B-load row: 0..15
    const int nc = (tid & 15) << 2;   // B-load col: 0..60

    for (int k0 = 0; k0 < KA; k0 += BK) {
        float4 a4;
        if (GATHER) {
            const int hi  = k0 >> 8;                       // head index (k/256)
            const int row = gidx[(m0 + lr) * KH + hi];
            a4 = *reinterpret_cast<const float4*>(A + (size_t)row * DL + (k0 & (DL - 1)) + lc);
        } else {
            a4 = *reinterpret_cast<const float4*>(A + (size_t)(m0 + lr) * KA + k0 + lc);
        }
        const float4 b4 = *reinterpret_cast<const float4*>(Bm + (size_t)(k0 + kr) * N + n0 + nc);
        As[lc + 0][lr] = a4.x; As[lc + 1][lr] = a4.y;
        As[lc + 2][lr] = a4.z; As[lc + 3][lr] = a4.w;
        *reinterpret_cast<float4*>(&Bs[kr][nc]) = b4;
        __syncthreads();
        #pragma unroll
        for (int kk = 0; kk < BK; ++kk) {
            const float4 av = *reinterpret_cast<const float4*>(&As[kk][ty << 2]);
            const float4 bv = *reinterpret_cast<const float4*>(&Bs[kk][tx << 2]);
            const float a[4] = {av.x, av.y, av.z, av.w};
            const float b[4] = {bv.x, bv.y, bv.z, bv.w};
            #pragma unroll
            for (int i = 0; i < 4; ++i)
                #pragma unroll
                for (int j = 0; j < 4; ++j)
                    acc[i][j] = fmaf(a[i], b[j], acc[i][j]);
        }
        __syncthreads();
    }

    if (TRANSOUT) {
        #pragma unroll
        for (int i = 0; i < 4; ++i) {
            const int m = m0 + (ty << 2) + i;
            const int b = m >> 12, s = m & (S_ - 1);
            #pragma unroll
            for (int j = 0; j < 4; ++j) {
                const int n = n0 + (tx << 2) + j;
                C[(size_t)(b * N + n) * S_ + s] = acc[i][j];
            }
        }
    } else {
        float4 bv = make_float4(0.f, 0.f, 0.f, 0.f);
        if (FUSE) bv = *reinterpret_cast<const float4*>(bias + n0 + (tx << 2));
        #pragma unroll
        for (int i = 0; i < 4; ++i) {
            const int m = m0 + (ty << 2) + i;
            float4 o;
            o.x = acc[i][0] + bv.x; o.y = acc[i][1] + bv.y;
            o.z = acc[i][2] + bv.z; o.w = acc[i][3] + bv.w;
            if (FUSE) {
                o.x = fmaxf(o.x, 0.f); o.y = fmaxf(o.y, 0.f);
                o.z = fmaxf(o.z, 0.f); o.w = fmaxf(o.w, 0.f);
            }
            *reinterpret_cast<float4*>(C + (size_t)m * N + n0 + (tx << 2)) = o;
        }
    }
}

// ---------------------------------------------------------------------------
// Per-(b,k) variance of RMVsT row (contiguous over s).
// ---------------------------------------------------------------------------
__global__ __launch_bounds__(256)
void var_kernel(const float* __restrict__ rmvT, float* __restrict__ hvars)
{
    const int bk = blockIdx.x;
    const float* src = rmvT + (size_t)bk * S_;
    float s1 = 0.f, s2 = 0.f;
    for (int t = threadIdx.x; t < S_; t += 256) {
        const float v = src[t];
        s1 += v; s2 += v * v;
    }
    #pragma unroll
    for (int off = 32; off; off >>= 1) {
        s1 += __shfl_xor(s1, off);
        s2 += __shfl_xor(s2, off);
    }
    __shared__ float r1[4], r2[4];
    const int wave = threadIdx.x >> 6, lane = threadIdx.x & 63;
    if (lane == 0) { r1[wave] = s1; r2[wave] = s2; }
    __syncthreads();
    if (threadIdx.x == 0) {
        const float t1 = r1[0] + r1[1] + r1[2] + r1[3];
        const float t2 = r2[0] + r2[1] + r2[2] + r2[3];
        const float mu = t1 / (float)S_;
        hvars[bk] = t2 / (float)S_ - mu * mu;
    }
}

// ---------------------------------------------------------------------------
// Stable top-KH selection per batch (ties -> smaller index, matches stable
// argsort of -h_vars).
// ---------------------------------------------------------------------------
__global__ void topk_kernel(const float* __restrict__ hvars, int* __restrict__ topidx)
{
    const int b = threadIdx.x;
    if (b >= B_) return;
    float v[KK];
    for (int k = 0; k < KK; ++k) v[k] = hvars[b * KK + k];
    for (int i = 0; i < KH; ++i) {
        int best = 0; float bv = -3.4e38f;
        for (int k = 0; k < KK; ++k)
            if (v[k] > bv) { bv = v[k]; best = k; }
        topidx[b * KH + i] = best;
        v[best] = -3.4e38f;
    }
}

// ---------------------------------------------------------------------------
// Bitonic argsort (ascending, stable via (key,idx) composite) of one RMVsT
// row of S_=4096 values. One block per (b, head). Emits the gather table
// gidx[(b*S_+j)*KH + i] = b*S_ + idx[j] consumed by the gathered GEMM.
// ---------------------------------------------------------------------------
__global__ __launch_bounds__(1024)
void sort_kernel(const float* __restrict__ rmvT, const int* __restrict__ topidx,
                 int* __restrict__ gidx)
{
    const int b = blockIdx.x >> 2;
    const int i = blockIdx.x & 3;
    __shared__ float key[S_];
    __shared__ int   idx[S_];
    const int k = topidx[b * KH + i];
    const float* src = rmvT + (size_t)(b * KK + k) * S_;
    for (int t = threadIdx.x; t < S_; t += 1024) { key[t] = src[t]; idx[t] = t; }
    __syncthreads();
    for (int sz = 2; sz <= S_; sz <<= 1) {
        for (int st = sz >> 1; st > 0; st >>= 1) {
            for (int t = threadIdx.x; t < S_; t += 1024) {
                const int l = t ^ st;
                if (l > t) {
                    const float ka = key[t], kb = key[l];
                    const int   ia = idx[t], ib = idx[l];
                    const bool agtb = (ka > kb) || (ka == kb && ia > ib);
                    const bool up = ((t & sz) == 0);
                    if (up ? agtb : !agtb) {
                        key[t] = kb; key[l] = ka;
                        idx[t] = ib; idx[l] = ia;
                    }
                }
            }
            __syncthreads();
        }
    }
    for (int j = threadIdx.x; j < S_; j += 1024)
        gidx[((b << 12) + j) * KH + i] = (b << 12) + idx[j];
}

// ---------------------------------------------------------------------------
// Windowed softmax scores: one wave per (b,s); 9 dot products of length 256.
// ---------------------------------------------------------------------------
__global__ __launch_bounds__(64)
void score_kernel(const float* __restrict__ q2, float* __restrict__ scores)
{
    const int m = blockIdx.x;
    const int s = m & (S_ - 1), b = m >> 12;
    const int lane = threadIdx.x;
    const float4 qv = *reinterpret_cast<const float4*>(q2 + (size_t)m * DL + (lane << 2));
    const int jb = (s < (WW - 1) / 2) ? 0 : (s >= S_ - (WW - 1) / 2 ? S_ - WW : s - (WW - 1) / 2);
    const float* kbase = q2 + (size_t)(b * S_ + jb) * DL;
    float sc[WW];
    #pragma unroll
    for (int w = 0; w < WW; ++w) {
        const float4 kv = *reinterpret_cast<const float4*>(kbase + w * DL + (lane << 2));
        float d = qv.x * kv.x + qv.y * kv.y + qv.z * kv.z + qv.w * kv.w;
        #pragma unroll
        for (int off = 32; off; off >>= 1) d += __shfl_xor(d, off);
        sc[w] = d * 0.0625f;   // / sqrt(256)
    }
    float mx = sc[0];
    #pragma unroll
    for (int w = 1; w < WW; ++w) mx = fmaxf(mx, sc[w]);
    float sum = 0.f;
    #pragma unroll
    for (int w = 0; w < WW; ++w) { sc[w] = __expf(sc[w] - mx); sum += sc[w]; }
    const float inv = 1.f / sum;
    if (lane == 0) {
        #pragma unroll
        for (int w = 0; w < WW; ++w) scores[m * WW + w] = sc[w] * inv;
    }
}

// ---------------------------------------------------------------------------
// out = LayerNorm( sum_w scores[w] * v[j(s,w)] + inputs ). One block per row.
// ---------------------------------------------------------------------------
__global__ __launch_bounds__(256)
void final_kernel(const float* __restrict__ v, const float* __restrict__ scores,
                  const float* __restrict__ inputs, const float* __restrict__ gamma,
                  const float* __restrict__ beta, float* __restrict__ out)
{
    const int m = blockIdx.x;
    const int s = m & (S_ - 1), b = m >> 12;
    const int tid = threadIdx.x;
    __shared__ float sc_s[WW];
    __shared__ float r1[4], r2[4];
    __shared__ float mu_s, rs_s;
    if (tid < WW) sc_s[tid] = scores[m * WW + tid];
    __syncthreads();
    const int jb = (s < (WW - 1) / 2) ? 0 : (s >= S_ - (WW - 1) / 2 ? S_ - WW : s - (WW - 1) / 2);
    const float* vb  = v + (size_t)(b * S_ + jb) * DH;
    const float* inp = inputs + (size_t)m * DH;
    float x[4];
    float s1 = 0.f, s2 = 0.f;
    #pragma unroll
    for (int c = 0; c < 4; ++c) {
        const int h = tid + (c << 8);
        float acc = 0.f;
        #pragma unroll
        for (int w = 0; w < WW; ++w) acc = fmaf(sc_s[w], vb[w * DH + h], acc);
        acc += inp[h];
        x[c] = acc;
        s1 += acc; s2 += acc * acc;
    }
    #pragma unroll
    for (int off = 32; off; off >>= 1) {
        s1 += __shfl_xor(s1, off);
        s2 += __shfl_xor(s2, off);
    }
    const int wave = tid >> 6, lane = tid & 63;
    if (lane == 0) { r1[wave] = s1; r2[wave] = s2; }
    __syncthreads();
    if (tid == 0) {
        const float t1 = r1[0] + r1[1] + r1[2] + r1[3];
        const float t2 = r2[0] + r2[1] + r2[2] + r2[3];
        const float mu = t1 / (float)DH;
        mu_s = mu;
        rs_s = rsqrtf(t2 / (float)DH - mu * mu + 0.001f);
    }
    __syncthreads();
    const float mu = mu_s, rs = rs_s;
    #pragma unroll
    for (int c = 0; c < 4; ++c) {
        const int h = tid + (c << 8);
        out[(size_t)m * DH + h] = gamma[h] * (x[c] - mu) * rs + beta[h];
    }
}

// ---------------------------------------------------------------------------
extern "C" void kernel_launch(void* const* d_in, const int* in_sizes, int n_in,
                              void* d_out, int out_size, void* d_ws, size_t ws_size,
                              hipStream_t stream)
{
    (void)in_sizes; (void)n_in; (void)out_size; (void)ws_size;
    const float* inputs = (const float*)d_in[0];
    const float* W1     = (const float*)d_in[1];
    const float* b1     = (const float*)d_in[2];
    const float* RME    = (const float*)d_in[3];
    const float* K2     = (const float*)d_in[4];
    const float* b2     = (const float*)d_in[5];
    const float* Wu     = (const float*)d_in[6];
    const float* bu     = (const float*)d_in[7];
    const float* gamma  = (const float*)d_in[8];
    const float* beta   = (const float*)d_in[9];
    float* out = (float*)d_out;

    char* ws = (char*)d_ws;
    // Workspace layout (~100.3 MB):
    float* q      = (float*)(ws);                              // 16 MB  [M x 256]
    float* q2     = (float*)(ws + (16u  << 20));               // 16 MB  [M x 256]
    float* v      = (float*)(ws + (32u  << 20));               // 64 MB  [M x 1024]
    float* rmvT   = (float*)(ws + (96u  << 20));               // 4 MB   [B][K][S]
    float* scores = (float*)(ws + (96u  << 20));               // alias rmvT (dead after sort)
    float* hvars  = (float*)(ws + (100u << 20));               // 1 KB
    int*   topidx = (int*)  (ws + (100u << 20) + 4096);        // 64 B
    int*   gidx   = (int*)  (ws + (100u << 20) + 8192);        // 256 KB [M][KH]

    const int M = B_ * S_;
    const dim3 blk(256);

    // 1. q = relu(inputs @ W1 + b1)
    gemm_kernel<false, true, false><<<dim3(DL / 64, M / 64), blk, 0, stream>>>(
        inputs, W1, b1, q, nullptr, M, DH, DL);
    // 2. RMVsT[b][k][s] = (q @ RME)^T
    gemm_kernel<false, false, true><<<dim3(KK / 64, M / 64), blk, 0, stream>>>(
        q, RME, nullptr, rmvT, nullptr, M, DL, KK);
    // 3. per-(b,k) variance over s
    var_kernel<<<dim3(B_ * KK), blk, 0, stream>>>(rmvT, hvars);
    // 4. top-4 variance heads per batch
    topk_kernel<<<dim3(1), dim3(64), 0, stream>>>(hvars, topidx);
    // 5. stable argsort of each selected head row -> gather table
    sort_kernel<<<dim3(B_ * KH), dim3(1024), 0, stream>>>(rmvT, topidx, gidx);
    // 6. q2 = relu(gather(q) @ K2r + b2)   (gathered-A GEMM, K = KH*DL)
    gemm_kernel<true, true, false><<<dim3(DL / 64, M / 64), blk, 0, stream>>>(
        q, (const float*)K2, b2, q2, gidx, M, KH * DL, DL);
    // 7. v = relu(q2 @ Wu + bu)   (shared across all windows: 9x FLOP saving)
    gemm_kernel<false, true, false><<<dim3(DH / 64, M / 64), blk, 0, stream>>>(
        q2, Wu, bu, v, nullptr, M, DL, DH);
    // 8. windowed softmax scores
    score_kernel<<<dim3(M), dim3(64), 0, stream>>>(q2, scores);
    // 9. weighted window sum of v + residual + LayerNorm
    final_kernel<<<dim3(M), blk, 0, stream>>>(v, scores, inputs, gamma, beta, out);
}

// Round 3
// 442.353 us; speedup vs baseline: 1.2798x; 1.2798x over previous
//
#include <hip/hip_runtime.h>

#define B_  4
#define S_  4096
#define DH  1024
#define DL  256
#define KK  64
#define KH  4
#define WW  9

typedef unsigned short ushort_t;
typedef __bf16 bf16x8 __attribute__((ext_vector_type(8)));
typedef float  f32x4  __attribute__((ext_vector_type(4)));

__device__ __forceinline__ void gld_lds16(const void* g, void* lds_uniform_base) {
    __builtin_amdgcn_global_load_lds(
        (const __attribute__((address_space(1))) unsigned int*)g,
        (__attribute__((address_space(3))) unsigned int*)lds_uniform_base,
        16, 0, 0);
}

// ---------------------------------------------------------------------------
// Limb-decomposed bf16 MFMA GEMM.  C = relu(sum_p A[pa[p]] * B[pb[p]] + bias)
// A limbs: [M][K] bf16 (row-major).  B limbs: [N][K] bf16 (pre-transposed).
// NPASS=3: ah*bh + al*bh + ah*bl (fp16-class inputs -> ~3e-5 rel err)
// NPASS=6: 3-limb, fp32-equivalent accuracy (for the sort-key path).
// BM=64, BN=128, BK=64, 256 threads, 4 waves in 2x2, wave tile 32x64.
// LDS XOR-swizzled (kblk ^= row&7) on both staging-source and read side.
// ---------------------------------------------------------------------------
template<int NPASS, bool GATHER, bool LIMBS>
__global__ __launch_bounds__(256)
void mfma_gemm(const ushort_t* __restrict__ A0, const ushort_t* __restrict__ A1,
               const ushort_t* __restrict__ A2,
               const ushort_t* __restrict__ B0, const ushort_t* __restrict__ B1,
               const ushort_t* __restrict__ B2,
               const float* __restrict__ bias, float* __restrict__ C,
               ushort_t* __restrict__ Ch, ushort_t* __restrict__ Cl,
               const int* __restrict__ gidx, int K, int N)
{
    __shared__ __align__(16) ushort_t As[64 * 64];    // 8 KB
    __shared__ __align__(16) ushort_t Bs[128 * 64];   // 16 KB

    const int tid = threadIdx.x;
    const int w = tid >> 6, l = tid & 63;
    const int wm = w >> 1, wn = w & 1;
    const int lr = l & 15, lk = l >> 4;
    const int m0 = blockIdx.y * 64, n0 = blockIdx.x * 128;

    const ushort_t* const Al[3] = {A0, A1, A2};
    const ushort_t* const Bl[3] = {B0, B1, B2};
    static constexpr int pa6[6] = {0,0,1,1,0,2};
    static constexpr int pb6[6] = {0,1,0,1,2,0};
    static constexpr int pa3[6] = {0,1,0,0,0,0};
    static constexpr int pb3[6] = {0,0,1,0,0,0};

    f32x4 acc[2][4] = {};

    #pragma unroll 1
    for (int p = 0; p < NPASS; ++p) {
        const int ia = (NPASS == 6) ? pa6[p] : pa3[p];
        const int ib = (NPASS == 6) ? pb6[p] : pb3[p];
        const ushort_t* Ap = Al[ia];
        const ushort_t* Bp = Bl[ib];
        for (int k0 = 0; k0 < K; k0 += 64) {
            // ---- stage A tile (64x64): 512 chunks of 16B, 2 per thread ----
            #pragma unroll
            for (int it = 0; it < 2; ++it) {
                const int c = it * 256 + w * 64 + l;
                const int r = c >> 3, kp = c & 7;
                const int kl = kp ^ (r & 7);
                const ushort_t* src;
                if (GATHER) {
                    const int rg = gidx[(m0 + r) * KH + (k0 >> 8)];
                    src = Ap + (size_t)rg * DL + (k0 & (DL - 1)) + kl * 8;
                } else {
                    src = Ap + (size_t)(m0 + r) * K + k0 + kl * 8;
                }
                gld_lds16(src, &As[(size_t)(it * 256 + w * 64) * 8]);
            }
            // ---- stage B tile (128x64): 1024 chunks, 4 per thread ----
            #pragma unroll
            for (int it = 0; it < 4; ++it) {
                const int c = it * 256 + w * 64 + l;
                const int r = c >> 3, kp = c & 7;
                const int kl = kp ^ (r & 7);
                const ushort_t* src = Bp + (size_t)(n0 + r) * K + k0 + kl * 8;
                gld_lds16(src, &Bs[(size_t)(it * 256 + w * 64) * 8]);
            }
            __syncthreads();   // compiler drains vmcnt+lgkmcnt before s_barrier

            bf16x8 a[2][2], b[2][4];
            #pragma unroll
            for (int mf = 0; mf < 2; ++mf)
                #pragma unroll
                for (int ks = 0; ks < 2; ++ks) {
                    const int row = wm * 32 + mf * 16 + lr;
                    const int kb  = ks * 4 + lk;
                    a[mf][ks] = *(const bf16x8*)&As[row * 64 + ((kb ^ (row & 7)) << 3)];
                }
            #pragma unroll
            for (int nf = 0; nf < 4; ++nf)
                #pragma unroll
                for (int ks = 0; ks < 2; ++ks) {
                    const int row = wn * 64 + nf * 16 + lr;
                    const int kb  = ks * 4 + lk;
                    b[ks][nf] = *(const bf16x8*)&Bs[row * 64 + ((kb ^ (row & 7)) << 3)];
                }
            #pragma unroll
            for (int ks = 0; ks < 2; ++ks)
                #pragma unroll
                for (int mf = 0; mf < 2; ++mf)
                    #pragma unroll
                    for (int nf = 0; nf < 4; ++nf)
                        acc[mf][nf] = __builtin_amdgcn_mfma_f32_16x16x32_bf16(
                            a[mf][ks], b[ks][nf], acc[mf][nf], 0, 0, 0);
            __syncthreads();
        }
    }

    // ---- epilogue: bias + relu, fp32 out (+ optional bf16 hi/lo limbs) ----
    float bv[4];
    #pragma unroll
    for (int nf = 0; nf < 4; ++nf)
        bv[nf] = bias[n0 + wn * 64 + nf * 16 + lr];
    #pragma unroll
    for (int mf = 0; mf < 2; ++mf)
        #pragma unroll
        for (int nf = 0; nf < 4; ++nf)
            #pragma unroll
            for (int r = 0; r < 4; ++r) {
                const int m = m0 + wm * 32 + mf * 16 + lk * 4 + r;
                const int n = n0 + wn * 64 + nf * 16 + lr;
                float x = acc[mf][nf][r] + bv[nf];
                x = fmaxf(x, 0.f);
                C[(size_t)m * N + n] = x;
                if (LIMBS) {
                    const __bf16 h = (__bf16)x;
                    const __bf16 lo = (__bf16)(x - (float)h);
                    Ch[(size_t)m * N + n] = __builtin_bit_cast(ushort_t, h);
                    Cl[(size_t)m * N + n] = __builtin_bit_cast(ushort_t, lo);
                }
            }
}

// ---------------------------------------------------------------------------
// 3-limb elementwise split: fp32 -> bf16 a0,a1,a2 (exact 24-bit decomposition)
// ---------------------------------------------------------------------------
__global__ __launch_bounds__(256)
void split3_kernel(const float* __restrict__ in, ushort_t* __restrict__ a0,
                   ushort_t* __restrict__ a1, ushort_t* __restrict__ a2, int n4)
{
    for (int i = blockIdx.x * 256 + threadIdx.x; i < n4; i += gridDim.x * 256) {
        const float4 x = ((const float4*)in)[i];
        const float xs[4] = {x.x, x.y, x.z, x.w};
        unsigned int p0[2], p1[2], p2[2];
        ushort_t h0[4], h1[4], h2[4];
        #pragma unroll
        for (int j = 0; j < 4; ++j) {
            const __bf16 b0v = (__bf16)xs[j];
            const float r1 = xs[j] - (float)b0v;
            const __bf16 b1v = (__bf16)r1;
            const float r2 = r1 - (float)b1v;
            const __bf16 b2v = (__bf16)r2;
            h0[j] = __builtin_bit_cast(ushort_t, b0v);
            h1[j] = __builtin_bit_cast(ushort_t, b1v);
            h2[j] = __builtin_bit_cast(ushort_t, b2v);
        }
        p0[0] = h0[0] | ((unsigned)h0[1] << 16); p0[1] = h0[2] | ((unsigned)h0[3] << 16);
        p1[0] = h1[0] | ((unsigned)h1[1] << 16); p1[1] = h1[2] | ((unsigned)h1[3] << 16);
        p2[0] = h2[0] | ((unsigned)h2[1] << 16); p2[1] = h2[2] | ((unsigned)h2[3] << 16);
        *(uint2*)&a0[(size_t)i * 4] = make_uint2(p0[0], p0[1]);
        *(uint2*)&a1[(size_t)i * 4] = make_uint2(p1[0], p1[1]);
        *(uint2*)&a2[(size_t)i * 4] = make_uint2(p2[0], p2[1]);
    }
}

// ---------------------------------------------------------------------------
// Transpose + 3-limb split: in [K][N] fp32 -> t0/t1/t2 [N][K] bf16.
// LDS-tiled 32x32 so both sides stay coalesced.
// ---------------------------------------------------------------------------
__global__ __launch_bounds__(256)
void tsplit_kernel(const float* __restrict__ in, ushort_t* __restrict__ t0,
                   ushort_t* __restrict__ t1, ushort_t* __restrict__ t2, int K, int N)
{
    __shared__ float tile[32][33];
    const int t = threadIdx.x;
    const int bk = blockIdx.x * 32, bn = blockIdx.y * 32;
    const int c = t & 31, rb = t >> 5;
    #pragma unroll
    for (int i = 0; i < 4; ++i) {
        const int r = rb + i * 8;
        tile[r][c] = in[(size_t)(bk + r) * N + bn + c];
    }
    __syncthreads();
    #pragma unroll
    for (int i = 0; i < 4; ++i) {
        const int rr = rb + i * 8;        // output row (n)
        const float x = tile[c][rr];
        const __bf16 b0v = (__bf16)x;
        const float r1 = x - (float)b0v;
        const __bf16 b1v = (__bf16)r1;
        const float r2 = r1 - (float)b1v;
        const __bf16 b2v = (__bf16)r2;
        const size_t o = (size_t)(bn + rr) * K + bk + c;
        t0[o] = __builtin_bit_cast(ushort_t, b0v);
        t1[o] = __builtin_bit_cast(ushort_t, b1v);
        t2[o] = __builtin_bit_cast(ushort_t, b2v);
    }
}

// ---------------------------------------------------------------------------
// fp32 tiled GEMM (kept for RMVs = q @ RME, transposed-out [b][k][s]).
// ---------------------------------------------------------------------------
__global__ __launch_bounds__(256)
void gemm_trans_kernel(const float* __restrict__ A, const float* __restrict__ Bm,
                       float* __restrict__ C, int M, int KA, int N)
{
    constexpr int BK = 16;
    __shared__ float Asb[BK][64 + 4];
    __shared__ float Bsb[BK][64 + 4];
    const int tid = threadIdx.x;
    const int tx = tid & 15, ty = tid >> 4;
    const int m0 = blockIdx.y * 64, n0 = blockIdx.x * 64;

    float acc[4][4] = {};
    const int lr = tid >> 2, lc = (tid & 3) << 2;
    const int kr = tid >> 4, nc = (tid & 15) << 2;

    for (int k0 = 0; k0 < KA; k0 += BK) {
        const float4 a4 = *reinterpret_cast<const float4*>(A + (size_t)(m0 + lr) * KA + k0 + lc);
        const float4 b4 = *reinterpret_cast<const float4*>(Bm + (size_t)(k0 + kr) * N + n0 + nc);
        Asb[lc + 0][lr] = a4.x; Asb[lc + 1][lr] = a4.y;
        Asb[lc + 2][lr] = a4.z; Asb[lc + 3][lr] = a4.w;
        *reinterpret_cast<float4*>(&Bsb[kr][nc]) = b4;
        __syncthreads();
        #pragma unroll
        for (int kk = 0; kk < BK; ++kk) {
            const float4 av = *reinterpret_cast<const float4*>(&Asb[kk][ty << 2]);
            const float4 bv = *reinterpret_cast<const float4*>(&Bsb[kk][tx << 2]);
            const float a[4] = {av.x, av.y, av.z, av.w};
            const float b[4] = {bv.x, bv.y, bv.z, bv.w};
            #pragma unroll
            for (int i = 0; i < 4; ++i)
                #pragma unroll
                for (int j = 0; j < 4; ++j)
                    acc[i][j] = fmaf(a[i], b[j], acc[i][j]);
        }
        __syncthreads();
    }
    #pragma unroll
    for (int i = 0; i < 4; ++i) {
        const int m = m0 + (ty << 2) + i;
        const int b = m >> 12, s = m & (S_ - 1);
        #pragma unroll
        for (int j = 0; j < 4; ++j) {
            const int n = n0 + (tx << 2) + j;
            C[(size_t)(b * N + n) * S_ + s] = acc[i][j];
        }
    }
}

// ---------------------------------------------------------------------------
__global__ __launch_bounds__(256)
void var_kernel(const float* __restrict__ rmvT, float* __restrict__ hvars)
{
    const int bk = blockIdx.x;
    const float* src = rmvT + (size_t)bk * S_;
    float s1 = 0.f, s2 = 0.f;
    for (int t = threadIdx.x; t < S_; t += 256) {
        const float v = src[t];
        s1 += v; s2 += v * v;
    }
    #pragma unroll
    for (int off = 32; off; off >>= 1) {
        s1 += __shfl_xor(s1, off);
        s2 += __shfl_xor(s2, off);
    }
    __shared__ float r1[4], r2[4];
    const int wave = threadIdx.x >> 6, lane = threadIdx.x & 63;
    if (lane == 0) { r1[wave] = s1; r2[wave] = s2; }
    __syncthreads();
    if (threadIdx.x == 0) {
        const float t1 = r1[0] + r1[1] + r1[2] + r1[3];
        const float t2 = r2[0] + r2[1] + r2[2] + r2[3];
        const float mu = t1 / (float)S_;
        hvars[bk] = t2 / (float)S_ - mu * mu;
    }
}

__global__ void topk_kernel(const float* __restrict__ hvars, int* __restrict__ topidx)
{
    const int b = threadIdx.x;
    if (b >= B_) return;
    float v[KK];
    for (int k = 0; k < KK; ++k) v[k] = hvars[b * KK + k];
    for (int i = 0; i < KH; ++i) {
        int best = 0; float bv = -3.4e38f;
        for (int k = 0; k < KK; ++k)
            if (v[k] > bv) { bv = v[k]; best = k; }
        topidx[b * KH + i] = best;
        v[best] = -3.4e38f;
    }
}

__global__ __launch_bounds__(1024)
void sort_kernel(const float* __restrict__ rmvT, const int* __restrict__ topidx,
                 int* __restrict__ gidx)
{
    const int b = blockIdx.x >> 2;
    const int i = blockIdx.x & 3;
    __shared__ float key[S_];
    __shared__ int   idx[S_];
    const int k = topidx[b * KH + i];
    const float* src = rmvT + (size_t)(b * KK + k) * S_;
    for (int t = threadIdx.x; t < S_; t += 1024) { key[t] = src[t]; idx[t] = t; }
    __syncthreads();
    for (int sz = 2; sz <= S_; sz <<= 1) {
        for (int st = sz >> 1; st > 0; st >>= 1) {
            for (int t = threadIdx.x; t < S_; t += 1024) {
                const int l = t ^ st;
                if (l > t) {
                    const float ka = key[t], kb = key[l];
                    const int   ia = idx[t], ib = idx[l];
                    const bool agtb = (ka > kb) || (ka == kb && ia > ib);
                    const bool up = ((t & sz) == 0);
                    if (up ? agtb : !agtb) {
                        key[t] = kb; key[l] = ka;
                        idx[t] = ib; idx[l] = ia;
                    }
                }
            }
            __syncthreads();
        }
    }
    for (int j = threadIdx.x; j < S_; j += 1024)
        gidx[((b << 12) + j) * KH + i] = (b << 12) + idx[j];
}

__global__ __launch_bounds__(64)
void score_kernel(const float* __restrict__ q2, float* __restrict__ scores)
{
    const int m = blockIdx.x;
    const int s = m & (S_ - 1), b = m >> 12;
    const int lane = threadIdx.x;
    const float4 qv = *reinterpret_cast<const float4*>(q2 + (size_t)m * DL + (lane << 2));
    const int jb = (s < (WW - 1) / 2) ? 0 : (s >= S_ - (WW - 1) / 2 ? S_ - WW : s - (WW - 1) / 2);
    const float* kbase = q2 + (size_t)(b * S_ + jb) * DL;
    float sc[WW];
    #pragma unroll
    for (int w = 0; w < WW; ++w) {
        const float4 kv = *reinterpret_cast<const float4*>(kbase + w * DL + (lane << 2));
        float d = qv.x * kv.x + qv.y * kv.y + qv.z * kv.z + qv.w * kv.w;
        #pragma unroll
        for (int off = 32; off; off >>= 1) d += __shfl_xor(d, off);
        sc[w] = d * 0.0625f;
    }
    float mx = sc[0];
    #pragma unroll
    for (int w = 1; w < WW; ++w) mx = fmaxf(mx, sc[w]);
    float sum = 0.f;
    #pragma unroll
    for (int w = 0; w < WW; ++w) { sc[w] = __expf(sc[w] - mx); sum += sc[w]; }
    const float inv = 1.f / sum;
    if (lane == 0) {
        #pragma unroll
        for (int w = 0; w < WW; ++w) scores[m * WW + w] = sc[w] * inv;
    }
}

__global__ __launch_bounds__(256)
void final_kernel(const float* __restrict__ v, const float* __restrict__ scores,
                  const float* __restrict__ inputs, const float* __restrict__ gamma,
                  const float* __restrict__ beta, float* __restrict__ out)
{
    const int m = blockIdx.x;
    const int s = m & (S_ - 1), b = m >> 12;
    const int tid = threadIdx.x;
    __shared__ float sc_s[WW];
    __shared__ float r1[4], r2[4];
    __shared__ float mu_s, rs_s;
    if (tid < WW) sc_s[tid] = scores[m * WW + tid];
    __syncthreads();
    const int jb = (s < (WW - 1) / 2) ? 0 : (s >= S_ - (WW - 1) / 2 ? S_ - WW : s - (WW - 1) / 2);
    const float* vb  = v + (size_t)(b * S_ + jb) * DH;
    const float* inp = inputs + (size_t)m * DH;
    float x[4];
    float s1 = 0.f, s2 = 0.f;
    #pragma unroll
    for (int c = 0; c < 4; ++c) {
        const int h = tid + (c << 8);
        float acc = 0.f;
        #pragma unroll
        for (int w = 0; w < WW; ++w) acc = fmaf(sc_s[w], vb[w * DH + h], acc);
        acc += inp[h];
        x[c] = acc;
        s1 += acc; s2 += acc * acc;
    }
    #pragma unroll
    for (int off = 32; off; off >>= 1) {
        s1 += __shfl_xor(s1, off);
        s2 += __shfl_xor(s2, off);
    }
    const int wave = tid >> 6, lane = tid & 63;
    if (lane == 0) { r1[wave] = s1; r2[wave] = s2; }
    __syncthreads();
    if (tid == 0) {
        const float t1 = r1[0] + r1[1] + r1[2] + r1[3];
        const float t2 = r2[0] + r2[1] + r2[2] + r2[3];
        const float mu = t1 / (float)DH;
        mu_s = mu;
        rs_s = rsqrtf(t2 / (float)DH - mu * mu + 0.001f);
    }
    __syncthreads();
    const float mu = mu_s, rs = rs_s;
    #pragma unroll
    for (int c = 0; c < 4; ++c) {
        const int h = tid + (c << 8);
        out[(size_t)m * DH + h] = gamma[h] * (x[c] - mu) * rs + beta[h];
    }
}

// ---------------------------------------------------------------------------
extern "C" void kernel_launch(void* const* d_in, const int* in_sizes, int n_in,
                              void* d_out, int out_size, void* d_ws, size_t ws_size,
                              hipStream_t stream)
{
    (void)in_sizes; (void)n_in; (void)out_size; (void)ws_size;
    const float* inputs = (const float*)d_in[0];
    const float* W1     = (const float*)d_in[1];
    const float* b1     = (const float*)d_in[2];
    const float* RME    = (const float*)d_in[3];
    const float* K2     = (const float*)d_in[4];
    const float* b2     = (const float*)d_in[5];
    const float* Wu     = (const float*)d_in[6];
    const float* bu     = (const float*)d_in[7];
    const float* gamma  = (const float*)d_in[8];
    const float* beta   = (const float*)d_in[9];
    float* out = (float*)d_out;

    char* ws = (char*)d_ws;
    const size_t MB = 1u << 20;
    // in-limbs [0,96) live only during #1; aliased afterwards by v / q2 limbs.
    ushort_t* in0 = (ushort_t*)(ws + 0 * MB);      // 32MB
    ushort_t* in1 = (ushort_t*)(ws + 32 * MB);     // 32MB
    ushort_t* in2 = (ushort_t*)(ws + 64 * MB);     // 32MB
    float*    v   = (float*)   (ws + 0 * MB);      // 64MB  (alias in0/in1, after #1)
    ushort_t* q2h = (ushort_t*)(ws + 64 * MB);     // 8MB   (alias in2, after #1)
    ushort_t* q2l = (ushort_t*)(ws + 72 * MB);     // 8MB
    float*    q   = (float*)   (ws + 96 * MB);     // 16MB
    ushort_t* qh  = (ushort_t*)(ws + 112 * MB);    // 8MB
    ushort_t* ql  = (ushort_t*)(ws + 120 * MB);    // 8MB
    float*    q2  = (float*)   (ws + 128 * MB);    // 16MB
    float*    rmvT= (float*)   (ws + 144 * MB);    // 4MB
    float*    scores = rmvT;                        // dead after sort
    float*    hvars  = (float*)(ws + 148 * MB);
    int*      topidx = (int*)  (ws + 148 * MB + 4096);
    int*      gidx   = (int*)  (ws + 148 * MB + 8192);   // 256KB
    ushort_t* w1t0 = (ushort_t*)(ws + 149 * MB);
    ushort_t* w1t1 = w1t0 + (DH * DL);
    ushort_t* w1t2 = w1t1 + (DH * DL);
    ushort_t* k2t0 = w1t2 + (DH * DL);
    ushort_t* k2t1 = k2t0 + (KH * DL * DL);
    ushort_t* wut0 = k2t1 + (KH * DL * DL);
    ushort_t* wut1 = wut0 + (DL * DH);
    ushort_t* wut2 = wut1 + (DL * DH);   // scratch third limb (unused by 3-pass)

    const int M = B_ * S_;

    // 0a. 3-limb split of inputs (exact fp32 decomposition)
    split3_kernel<<<dim3(4096), dim3(256), 0, stream>>>(inputs, in0, in1, in2, M * DH / 4);
    // 0b. transpose+split weights: W1 [1024][256], K2 [1024][256], Wu [256][1024]
    tsplit_kernel<<<dim3(DH / 32, DL / 32), dim3(256), 0, stream>>>(W1, w1t0, w1t1, w1t2, DH, DL);
    tsplit_kernel<<<dim3(KH * DL / 32, DL / 32), dim3(256), 0, stream>>>((const float*)K2, k2t0, k2t1, wut2, KH * DL, DL);
    tsplit_kernel<<<dim3(DL / 32, DH / 32), dim3(256), 0, stream>>>(Wu, wut0, wut1, wut2, DL, DH);

    // 1. q = relu(inputs @ W1 + b1)  -- 6-pass (fp32-grade: feeds the sort keys)
    mfma_gemm<6, false, true><<<dim3(DL / 128, M / 64), dim3(256), 0, stream>>>(
        in0, in1, in2, w1t0, w1t1, w1t2, b1, q, qh, ql, nullptr, DH, DL);
    // 2. RMVsT[b][k][s] = (q @ RME)^T   (fp32 vector GEMM, key path)
    gemm_trans_kernel<<<dim3(KK / 64, M / 64), dim3(256), 0, stream>>>(q, RME, rmvT, M, DL, KK);
    // 3-5. variance, top-4 heads, stable argsort -> gather table
    var_kernel<<<dim3(B_ * KK), dim3(256), 0, stream>>>(rmvT, hvars);
    topk_kernel<<<dim3(1), dim3(64), 0, stream>>>(hvars, topidx);
    sort_kernel<<<dim3(B_ * KH), dim3(1024), 0, stream>>>(rmvT, topidx, gidx);
    // 6. q2 = relu(gather(q) @ K2 + b2)  -- 3-pass, gathered A rows
    mfma_gemm<3, true, true><<<dim3(DL / 128, M / 64), dim3(256), 0, stream>>>(
        qh, ql, nullptr, k2t0, k2t1, nullptr, b2, q2, q2h, q2l, gidx, KH * DL, DL);
    // 7. v = relu(q2 @ Wu + bu)  -- 3-pass
    mfma_gemm<3, false, false><<<dim3(DH / 128, M / 64), dim3(256), 0, stream>>>(
        q2h, q2l, nullptr, wut0, wut1, nullptr, bu, v, nullptr, nullptr, nullptr, DL, DH);
    // 8. windowed softmax scores
    score_kernel<<<dim3(M), dim3(64), 0, stream>>>(q2, scores);
    // 9. weighted window sum + residual + LayerNorm
    final_kernel<<<dim3(M), dim3(256), 0, stream>>>(v, scores, inputs, gamma, beta, out);
}

// Round 4
// 347.293 us; speedup vs baseline: 1.6301x; 1.2737x over previous
//
#include <hip/hip_runtime.h>

#define B_  4
#define S_  4096
#define DH  1024
#define DL  256
#define KK  64
#define KH  4
#define WW  9

typedef unsigned short ushort_t;
typedef _Float16 f16;
typedef _Float16 f16x8 __attribute__((ext_vector_type(8)));
typedef float  f32x4  __attribute__((ext_vector_type(4)));

__device__ __forceinline__ void gld_lds16(const void* g, void* lds_uniform_base) {
    __builtin_amdgcn_global_load_lds(
        (const __attribute__((address_space(1))) unsigned int*)g,
        (__attribute__((address_space(3))) unsigned int*)lds_uniform_base,
        16, 0, 0);
}

// ---------------------------------------------------------------------------
// Fused 2-limb fp16 MFMA GEMM.  A = ah + al/2048, B = bh + bl/2048 (al, bl
// stored pre-scaled by 2048 so they stay in fp16 normal range).
//   acc0 += ah*bh ;  acc1 += ah*bl + al*bh   (al*bl dropped, ~2^-22 rel)
//   C = relu(acc0 + acc1/2048 + bias)
// Single K-sweep stages all 4 limb tiles per K-step -> each limb read from
// HBM exactly once (was 6 passes / 202 MB FETCH in round 3).
// BM=64, BN=128, BK=64, 256 threads, 4 waves 2x2, wave tile 32x64.
// LDS XOR-swizzle (chunk ^= row&7) on both staging-source and read side.
// ---------------------------------------------------------------------------
template<bool GATHER, bool LIMBS>
__global__ __launch_bounds__(256)
void mfma_gemm2(const ushort_t* __restrict__ Ah, const ushort_t* __restrict__ Al,
                const ushort_t* __restrict__ Bh, const ushort_t* __restrict__ Bl,
                const float* __restrict__ bias, float* __restrict__ C,
                ushort_t* __restrict__ Ch, ushort_t* __restrict__ Cl,
                const int* __restrict__ gidx, int K, int N)
{
    __shared__ __align__(16) ushort_t Ash[64 * 64];    // 8 KB
    __shared__ __align__(16) ushort_t Asl[64 * 64];    // 8 KB
    __shared__ __align__(16) ushort_t Bsh[128 * 64];   // 16 KB
    __shared__ __align__(16) ushort_t Bsl[128 * 64];   // 16 KB

    const int tid = threadIdx.x;
    const int w = tid >> 6, l = tid & 63;
    const int wm = w >> 1, wn = w & 1;
    const int lr = l & 15, lk = l >> 4;
    const int m0 = blockIdx.y * 64, n0 = blockIdx.x * 128;

    f32x4 acc0[2][4] = {};
    f32x4 acc1[2][4] = {};

    for (int k0 = 0; k0 < K; k0 += 64) {
        // ---- stage A tiles (64x64 f16 each): 512 chunks of 16B, 2/thread ----
        #pragma unroll
        for (int it = 0; it < 2; ++it) {
            const int c = it * 256 + w * 64 + l;
            const int r = c >> 3, kp = c & 7;
            const int kl = kp ^ (r & 7);
            size_t off;
            if (GATHER) {
                const int rg = gidx[(m0 + r) * KH + (k0 >> 8)];
                off = (size_t)rg * DL + (k0 & (DL - 1)) + kl * 8;
            } else {
                off = (size_t)(m0 + r) * K + k0 + kl * 8;
            }
            gld_lds16(Ah + off, &Ash[(size_t)(it * 256 + w * 64) * 8]);
            gld_lds16(Al + off, &Asl[(size_t)(it * 256 + w * 64) * 8]);
        }
        // ---- stage B tiles (128x64 f16 each): 1024 chunks, 4/thread ----
        #pragma unroll
        for (int it = 0; it < 4; ++it) {
            const int c = it * 256 + w * 64 + l;
            const int r = c >> 3, kp = c & 7;
            const int kl = kp ^ (r & 7);
            const size_t off = (size_t)(n0 + r) * K + k0 + kl * 8;
            gld_lds16(Bh + off, &Bsh[(size_t)(it * 256 + w * 64) * 8]);
            gld_lds16(Bl + off, &Bsl[(size_t)(it * 256 + w * 64) * 8]);
        }
        __syncthreads();   // drains vmcnt+lgkmcnt before s_barrier

        #pragma unroll
        for (int ks = 0; ks < 2; ++ks) {
            f16x8 ah[2], al[2];
            #pragma unroll
            for (int mf = 0; mf < 2; ++mf) {
                const int row = wm * 32 + mf * 16 + lr;
                const int kb  = ks * 4 + lk;
                const int o   = row * 64 + ((kb ^ (row & 7)) << 3);
                ah[mf] = *(const f16x8*)&Ash[o];
                al[mf] = *(const f16x8*)&Asl[o];
            }
            #pragma unroll
            for (int nf = 0; nf < 4; ++nf) {
                const int row = wn * 64 + nf * 16 + lr;
                const int kb  = ks * 4 + lk;
                const int o   = row * 64 + ((kb ^ (row & 7)) << 3);
                const f16x8 bh = *(const f16x8*)&Bsh[o];
                const f16x8 bl = *(const f16x8*)&Bsl[o];
                #pragma unroll
                for (int mf = 0; mf < 2; ++mf) {
                    acc0[mf][nf] = __builtin_amdgcn_mfma_f32_16x16x32_f16(
                        ah[mf], bh, acc0[mf][nf], 0, 0, 0);
                    acc1[mf][nf] = __builtin_amdgcn_mfma_f32_16x16x32_f16(
                        ah[mf], bl, acc1[mf][nf], 0, 0, 0);
                    acc1[mf][nf] = __builtin_amdgcn_mfma_f32_16x16x32_f16(
                        al[mf], bh, acc1[mf][nf], 0, 0, 0);
                }
            }
        }
        __syncthreads();
    }

    // ---- epilogue: combine limbs, bias + relu, fp32 (+ fp16 limb) out ----
    float bv[4];
    #pragma unroll
    for (int nf = 0; nf < 4; ++nf)
        bv[nf] = bias[n0 + wn * 64 + nf * 16 + lr];
    #pragma unroll
    for (int mf = 0; mf < 2; ++mf)
        #pragma unroll
        for (int nf = 0; nf < 4; ++nf)
            #pragma unroll
            for (int r = 0; r < 4; ++r) {
                const int m = m0 + wm * 32 + mf * 16 + lk * 4 + r;
                const int n = n0 + wn * 64 + nf * 16 + lr;
                float x = acc0[mf][nf][r] + acc1[mf][nf][r] * (1.0f / 2048.0f) + bv[nf];
                x = fmaxf(x, 0.f);
                C[(size_t)m * N + n] = x;
                if (LIMBS) {
                    const f16 h = (f16)x;
                    const f16 lo = (f16)((x - (float)h) * 2048.0f);
                    Ch[(size_t)m * N + n] = __builtin_bit_cast(ushort_t, h);
                    Cl[(size_t)m * N + n] = __builtin_bit_cast(ushort_t, lo);
                }
            }
}

// ---------------------------------------------------------------------------
// 2-limb elementwise split: fp32 -> f16 h, f16 l*2048 (22-bit coverage)
// ---------------------------------------------------------------------------
__global__ __launch_bounds__(256)
void split2_kernel(const float* __restrict__ in, ushort_t* __restrict__ a0,
                   ushort_t* __restrict__ a1, int n4)
{
    for (int i = blockIdx.x * 256 + threadIdx.x; i < n4; i += gridDim.x * 256) {
        const float4 x = ((const float4*)in)[i];
        const float xs[4] = {x.x, x.y, x.z, x.w};
        ushort_t h0[4], h1[4];
        #pragma unroll
        for (int j = 0; j < 4; ++j) {
            const f16 hv = (f16)xs[j];
            const f16 lv = (f16)((xs[j] - (float)hv) * 2048.0f);
            h0[j] = __builtin_bit_cast(ushort_t, hv);
            h1[j] = __builtin_bit_cast(ushort_t, lv);
        }
        *(uint2*)&a0[(size_t)i * 4] = make_uint2(h0[0] | ((unsigned)h0[1] << 16),
                                                 h0[2] | ((unsigned)h0[3] << 16));
        *(uint2*)&a1[(size_t)i * 4] = make_uint2(h1[0] | ((unsigned)h1[1] << 16),
                                                 h1[2] | ((unsigned)h1[3] << 16));
    }
}

// ---------------------------------------------------------------------------
// Transpose + 2-limb split: in [K][N] fp32 -> t0/t1 [N][K] f16 (l scaled).
// ---------------------------------------------------------------------------
__global__ __launch_bounds__(256)
void tsplit2_kernel(const float* __restrict__ in, ushort_t* __restrict__ t0,
                    ushort_t* __restrict__ t1, int K, int N)
{
    __shared__ float tile[32][33];
    const int t = threadIdx.x;
    const int bk = blockIdx.x * 32, bn = blockIdx.y * 32;
    const int c = t & 31, rb = t >> 5;
    #pragma unroll
    for (int i = 0; i < 4; ++i) {
        const int r = rb + i * 8;
        tile[r][c] = in[(size_t)(bk + r) * N + bn + c];
    }
    __syncthreads();
    #pragma unroll
    for (int i = 0; i < 4; ++i) {
        const int rr = rb + i * 8;
        const float x = tile[c][rr];
        const f16 hv = (f16)x;
        const f16 lv = (f16)((x - (float)hv) * 2048.0f);
        const size_t o = (size_t)(bn + rr) * K + bk + c;
        t0[o] = __builtin_bit_cast(ushort_t, hv);
        t1[o] = __builtin_bit_cast(ushort_t, lv);
    }
}

// ---------------------------------------------------------------------------
// fp32 tiled GEMM (RMVs = q @ RME, transposed-out [b][k][s]).
// ---------------------------------------------------------------------------
__global__ __launch_bounds__(256)
void gemm_trans_kernel(const float* __restrict__ A, const float* __restrict__ Bm,
                       float* __restrict__ C, int M, int KA, int N)
{
    constexpr int BK = 16;
    __shared__ float Asb[BK][64 + 4];
    __shared__ float Bsb[BK][64 + 4];
    const int tid = threadIdx.x;
    const int tx = tid & 15, ty = tid >> 4;
    const int m0 = blockIdx.y * 64, n0 = blockIdx.x * 64;

    float acc[4][4] = {};
    const int lr = tid >> 2, lc = (tid & 3) << 2;
    const int kr = tid >> 4, nc = (tid & 15) << 2;

    for (int k0 = 0; k0 < KA; k0 += BK) {
        const float4 a4 = *reinterpret_cast<const float4*>(A + (size_t)(m0 + lr) * KA + k0 + lc);
        const float4 b4 = *reinterpret_cast<const float4*>(Bm + (size_t)(k0 + kr) * N + n0 + nc);
        Asb[lc + 0][lr] = a4.x; Asb[lc + 1][lr] = a4.y;
        Asb[lc + 2][lr] = a4.z; Asb[lc + 3][lr] = a4.w;
        *reinterpret_cast<float4*>(&Bsb[kr][nc]) = b4;
        __syncthreads();
        #pragma unroll
        for (int kk = 0; kk < BK; ++kk) {
            const float4 av = *reinterpret_cast<const float4*>(&Asb[kk][ty << 2]);
            const float4 bv = *reinterpret_cast<const float4*>(&Bsb[kk][tx << 2]);
            const float a[4] = {av.x, av.y, av.z, av.w};
            const float b[4] = {bv.x, bv.y, bv.z, bv.w};
            #pragma unroll
            for (int i = 0; i < 4; ++i)
                #pragma unroll
                for (int j = 0; j < 4; ++j)
                    acc[i][j] = fmaf(a[i], b[j], acc[i][j]);
        }
        __syncthreads();
    }
    #pragma unroll
    for (int i = 0; i < 4; ++i) {
        const int m = m0 + (ty << 2) + i;
        const int b = m >> 12, s = m & (S_ - 1);
        #pragma unroll
        for (int j = 0; j < 4; ++j) {
            const int n = n0 + (tx << 2) + j;
            C[(size_t)(b * N + n) * S_ + s] = acc[i][j];
        }
    }
}

// ---------------------------------------------------------------------------
__global__ __launch_bounds__(256)
void var_kernel(const float* __restrict__ rmvT, float* __restrict__ hvars)
{
    const int bk = blockIdx.x;
    const float* src = rmvT + (size_t)bk * S_;
    float s1 = 0.f, s2 = 0.f;
    for (int t = threadIdx.x; t < S_; t += 256) {
        const float v = src[t];
        s1 += v; s2 += v * v;
    }
    #pragma unroll
    for (int off = 32; off; off >>= 1) {
        s1 += __shfl_xor(s1, off);
        s2 += __shfl_xor(s2, off);
    }
    __shared__ float r1[4], r2[4];
    const int wave = threadIdx.x >> 6, lane = threadIdx.x & 63;
    if (lane == 0) { r1[wave] = s1; r2[wave] = s2; }
    __syncthreads();
    if (threadIdx.x == 0) {
        const float t1 = r1[0] + r1[1] + r1[2] + r1[3];
        const float t2 = r2[0] + r2[1] + r2[2] + r2[3];
        const float mu = t1 / (float)S_;
        hvars[bk] = t2 / (float)S_ - mu * mu;
    }
}

__global__ void topk_kernel(const float* __restrict__ hvars, int* __restrict__ topidx)
{
    const int b = threadIdx.x;
    if (b >= B_) return;
    float v[KK];
    for (int k = 0; k < KK; ++k) v[k] = hvars[b * KK + k];
    for (int i = 0; i < KH; ++i) {
        int best = 0; float bv = -3.4e38f;
        for (int k = 0; k < KK; ++k)
            if (v[k] > bv) { bv = v[k]; best = k; }
        topidx[b * KH + i] = best;
        v[best] = -3.4e38f;
    }
}

__global__ __launch_bounds__(1024)
void sort_kernel(const float* __restrict__ rmvT, const int* __restrict__ topidx,
                 int* __restrict__ gidx)
{
    const int b = blockIdx.x >> 2;
    const int i = blockIdx.x & 3;
    __shared__ float key[S_];
    __shared__ int   idx[S_];
    const int k = topidx[b * KH + i];
    const float* src = rmvT + (size_t)(b * KK + k) * S_;
    for (int t = threadIdx.x; t < S_; t += 1024) { key[t] = src[t]; idx[t] = t; }
    __syncthreads();
    for (int sz = 2; sz <= S_; sz <<= 1) {
        for (int st = sz >> 1; st > 0; st >>= 1) {
            for (int t = threadIdx.x; t < S_; t += 1024) {
                const int l = t ^ st;
                if (l > t) {
                    const float ka = key[t], kb = key[l];
                    const int   ia = idx[t], ib = idx[l];
                    const bool agtb = (ka > kb) || (ka == kb && ia > ib);
                    const bool up = ((t & sz) == 0);
                    if (up ? agtb : !agtb) {
                        key[t] = kb; key[l] = ka;
                        idx[t] = ib; idx[l] = ia;
                    }
                }
            }
            __syncthreads();
        }
    }
    for (int j = threadIdx.x; j < S_; j += 1024)
        gidx[((b << 12) + j) * KH + i] = (b << 12) + idx[j];
}

__global__ __launch_bounds__(64)
void score_kernel(const float* __restrict__ q2, float* __restrict__ scores)
{
    const int m = blockIdx.x;
    const int s = m & (S_ - 1), b = m >> 12;
    const int lane = threadIdx.x;
    const float4 qv = *reinterpret_cast<const float4*>(q2 + (size_t)m * DL + (lane << 2));
    const int jb = (s < (WW - 1) / 2) ? 0 : (s >= S_ - (WW - 1) / 2 ? S_ - WW : s - (WW - 1) / 2);
    const float* kbase = q2 + (size_t)(b * S_ + jb) * DL;
    float sc[WW];
    #pragma unroll
    for (int w = 0; w < WW; ++w) {
        const float4 kv = *reinterpret_cast<const float4*>(kbase + w * DL + (lane << 2));
        float d = qv.x * kv.x + qv.y * kv.y + qv.z * kv.z + qv.w * kv.w;
        #pragma unroll
        for (int off = 32; off; off >>= 1) d += __shfl_xor(d, off);
        sc[w] = d * 0.0625f;
    }
    float mx = sc[0];
    #pragma unroll
    for (int w = 1; w < WW; ++w) mx = fmaxf(mx, sc[w]);
    float sum = 0.f;
    #pragma unroll
    for (int w = 0; w < WW; ++w) { sc[w] = __expf(sc[w] - mx); sum += sc[w]; }
    const float inv = 1.f / sum;
    if (lane == 0) {
        #pragma unroll
        for (int w = 0; w < WW; ++w) scores[m * WW + w] = sc[w] * inv;
    }
}

__global__ __launch_bounds__(256)
void final_kernel(const float* __restrict__ v, const float* __restrict__ scores,
                  const float* __restrict__ inputs, const float* __restrict__ gamma,
                  const float* __restrict__ beta, float* __restrict__ out)
{
    const int m = blockIdx.x;
    const int s = m & (S_ - 1), b = m >> 12;
    const int tid = threadIdx.x;
    __shared__ float sc_s[WW];
    __shared__ float r1[4], r2[4];
    __shared__ float mu_s, rs_s;
    if (tid < WW) sc_s[tid] = scores[m * WW + tid];
    __syncthreads();
    const int jb = (s < (WW - 1) / 2) ? 0 : (s >= S_ - (WW - 1) / 2 ? S_ - WW : s - (WW - 1) / 2);
    const float* vb  = v + (size_t)(b * S_ + jb) * DH;
    const float* inp = inputs + (size_t)m * DH;
    float x[4];
    float s1 = 0.f, s2 = 0.f;
    #pragma unroll
    for (int c = 0; c < 4; ++c) {
        const int h = tid + (c << 8);
        float acc = 0.f;
        #pragma unroll
        for (int w = 0; w < WW; ++w) acc = fmaf(sc_s[w], vb[w * DH + h], acc);
        acc += inp[h];
        x[c] = acc;
        s1 += acc; s2 += acc * acc;
    }
    #pragma unroll
    for (int off = 32; off; off >>= 1) {
        s1 += __shfl_xor(s1, off);
        s2 += __shfl_xor(s2, off);
    }
    const int wave = tid >> 6, lane = tid & 63;
    if (lane == 0) { r1[wave] = s1; r2[wave] = s2; }
    __syncthreads();
    if (tid == 0) {
        const float t1 = r1[0] + r1[1] + r1[2] + r1[3];
        const float t2 = r2[0] + r2[1] + r2[2] + r2[3];
        const float mu = t1 / (float)DH;
        mu_s = mu;
        rs_s = rsqrtf(t2 / (float)DH - mu * mu + 0.001f);
    }
    __syncthreads();
    const float mu = mu_s, rs = rs_s;
    #pragma unroll
    for (int c = 0; c < 4; ++c) {
        const int h = tid + (c << 8);
        out[(size_t)m * DH + h] = gamma[h] * (x[c] - mu) * rs + beta[h];
    }
}

// ---------------------------------------------------------------------------
extern "C" void kernel_launch(void* const* d_in, const int* in_sizes, int n_in,
                              void* d_out, int out_size, void* d_ws, size_t ws_size,
                              hipStream_t stream)
{
    (void)in_sizes; (void)n_in; (void)out_size; (void)ws_size;
    const float* inputs = (const float*)d_in[0];
    const float* W1     = (const float*)d_in[1];
    const float* b1     = (const float*)d_in[2];
    const float* RME    = (const float*)d_in[3];
    const float* K2     = (const float*)d_in[4];
    const float* b2     = (const float*)d_in[5];
    const float* Wu     = (const float*)d_in[6];
    const float* bu     = (const float*)d_in[7];
    const float* gamma  = (const float*)d_in[8];
    const float* beta   = (const float*)d_in[9];
    float* out = (float*)d_out;

    char* ws = (char*)d_ws;
    const size_t MB = 1u << 20;
    // [0,64) MB: input limbs during GEMM#1; reused as v afterwards.
    ushort_t* inh = (ushort_t*)(ws + 0 * MB);      // 32MB
    ushort_t* inl = (ushort_t*)(ws + 32 * MB);     // 32MB
    float*    v   = (float*)   (ws + 0 * MB);      // 64MB (alias, after #1)
    float*    q   = (float*)   (ws + 64 * MB);     // 16MB
    ushort_t* qh  = (ushort_t*)(ws + 80 * MB);     // 8MB
    ushort_t* ql  = (ushort_t*)(ws + 88 * MB);     // 8MB
    float*    q2  = (float*)   (ws + 96 * MB);     // 16MB
    ushort_t* q2h = (ushort_t*)(ws + 112 * MB);    // 8MB
    ushort_t* q2l = (ushort_t*)(ws + 120 * MB);    // 8MB
    float*    rmvT= (float*)   (ws + 128 * MB);    // 4MB
    float*    scores = rmvT;                        // dead after sort
    float*    hvars  = (float*)(ws + 132 * MB);
    int*      topidx = (int*)  (ws + 132 * MB + 4096);
    int*      gidx   = (int*)  (ws + 132 * MB + 8192);   // 256KB
    ushort_t* w1th = (ushort_t*)(ws + 133 * MB);
    ushort_t* w1tl = w1th + (DH * DL);
    ushort_t* k2th = w1tl + (DH * DL);
    ushort_t* k2tl = k2th + (KH * DL * DL);
    ushort_t* wuth = k2tl + (KH * DL * DL);
    ushort_t* wutl = wuth + (DL * DH);

    const int M = B_ * S_;

    // 0a. 2-limb fp16 split of inputs
    split2_kernel<<<dim3(4096), dim3(256), 0, stream>>>(inputs, inh, inl, M * DH / 4);
    // 0b. transpose+split weights
    tsplit2_kernel<<<dim3(DH / 32, DL / 32), dim3(256), 0, stream>>>(W1, w1th, w1tl, DH, DL);
    tsplit2_kernel<<<dim3(KH * DL / 32, DL / 32), dim3(256), 0, stream>>>((const float*)K2, k2th, k2tl, KH * DL, DL);
    tsplit2_kernel<<<dim3(DL / 32, DH / 32), dim3(256), 0, stream>>>(Wu, wuth, wutl, DL, DH);

    // 1. q = relu(inputs @ W1 + b1)   (fused single-sweep, 22-bit products)
    mfma_gemm2<false, true><<<dim3(DL / 128, M / 64), dim3(256), 0, stream>>>(
        inh, inl, w1th, w1tl, b1, q, qh, ql, nullptr, DH, DL);
    // 2. RMVsT[b][k][s] = (q @ RME)^T  (fp32, key path)
    gemm_trans_kernel<<<dim3(KK / 64, M / 64), dim3(256), 0, stream>>>(q, RME, rmvT, M, DL, KK);
    // 3-5. variance, top-4 heads, stable argsort -> gather table
    var_kernel<<<dim3(B_ * KK), dim3(256), 0, stream>>>(rmvT, hvars);
    topk_kernel<<<dim3(1), dim3(64), 0, stream>>>(hvars, topidx);
    sort_kernel<<<dim3(B_ * KH), dim3(1024), 0, stream>>>(rmvT, topidx, gidx);
    // 6. q2 = relu(gather(q) @ K2 + b2)
    mfma_gemm2<true, true><<<dim3(DL / 128, M / 64), dim3(256), 0, stream>>>(
        qh, ql, k2th, k2tl, b2, q2, q2h, q2l, gidx, KH * DL, DL);
    // 7. v = relu(q2 @ Wu + bu)
    mfma_gemm2<false, false><<<dim3(DH / 128, M / 64), dim3(256), 0, stream>>>(
        q2h, q2l, wuth, wutl, bu, v, nullptr, nullptr, nullptr, DL, DH);
    // 8. windowed softmax scores
    score_kernel<<<dim3(M), dim3(64), 0, stream>>>(q2, scores);
    // 9. weighted window sum + residual + LayerNorm
    final_kernel<<<dim3(M), dim3(256), 0, stream>>>(v, scores, inputs, gamma, beta, out);
}

// Round 6
// 294.939 us; speedup vs baseline: 1.9195x; 1.1775x over previous
//
#include <hip/hip_runtime.h>

#define B_  4
#define S_  4096
#define DH  1024
#define DL  256
#define KK  64
#define KH  4
#define WW  9

typedef unsigned short ushort_t;
typedef _Float16 f16;
typedef _Float16 f16x8 __attribute__((ext_vector_type(8)));
typedef float  f32x4  __attribute__((ext_vector_type(4)));

__device__ __forceinline__ void gld_lds16(const void* g, void* lds_uniform_base) {
    __builtin_amdgcn_global_load_lds(
        (const __attribute__((address_space(1))) unsigned int*)g,
        (__attribute__((address_space(3))) unsigned int*)lds_uniform_base,
        16, 0, 0);
}

// ---------------------------------------------------------------------------
// Fused 2-limb fp16 MFMA GEMM.  A = ah + al/2048, B = bh + bl/2048 (al, bl
// stored pre-scaled by 2048 so they stay in fp16 normal range).
//   acc0 += ah*bh ;  acc1 += ah*bl + al*bh   (al*bl dropped, ~2^-22 rel)
//   C = relu(acc0 + acc1/2048 + bias)
// BM=64, BN=128, BK=64, 256 threads, 4 waves 2x2, wave tile 32x64.
// LDS XOR-swizzle (chunk ^= row&7) on both staging-source and read side.
// ---------------------------------------------------------------------------
template<bool GATHER, bool LIMBS>
__global__ __launch_bounds__(256)
void mfma_gemm2(const ushort_t* __restrict__ Ah, const ushort_t* __restrict__ Al,
                const ushort_t* __restrict__ Bh, const ushort_t* __restrict__ Bl,
                const float* __restrict__ bias, float* __restrict__ C,
                ushort_t* __restrict__ Ch, ushort_t* __restrict__ Cl,
                const int* __restrict__ gidx, int K, int N)
{
    __shared__ __align__(16) ushort_t Ash[64 * 64];    // 8 KB
    __shared__ __align__(16) ushort_t Asl[64 * 64];    // 8 KB
    __shared__ __align__(16) ushort_t Bsh[128 * 64];   // 16 KB
    __shared__ __align__(16) ushort_t Bsl[128 * 64];   // 16 KB

    const int tid = threadIdx.x;
    const int w = tid >> 6, l = tid & 63;
    const int wm = w >> 1, wn = w & 1;
    const int lr = l & 15, lk = l >> 4;
    const int m0 = blockIdx.y * 64, n0 = blockIdx.x * 128;

    f32x4 acc0[2][4] = {};
    f32x4 acc1[2][4] = {};

    for (int k0 = 0; k0 < K; k0 += 64) {
        #pragma unroll
        for (int it = 0; it < 2; ++it) {
            const int c = it * 256 + w * 64 + l;
            const int r = c >> 3, kp = c & 7;
            const int kl = kp ^ (r & 7);
            size_t off;
            if (GATHER) {
                const int rg = gidx[(m0 + r) * KH + (k0 >> 8)];
                off = (size_t)rg * DL + (k0 & (DL - 1)) + kl * 8;
            } else {
                off = (size_t)(m0 + r) * K + k0 + kl * 8;
            }
            gld_lds16(Ah + off, &Ash[(size_t)(it * 256 + w * 64) * 8]);
            gld_lds16(Al + off, &Asl[(size_t)(it * 256 + w * 64) * 8]);
        }
        #pragma unroll
        for (int it = 0; it < 4; ++it) {
            const int c = it * 256 + w * 64 + l;
            const int r = c >> 3, kp = c & 7;
            const int kl = kp ^ (r & 7);
            const size_t off = (size_t)(n0 + r) * K + k0 + kl * 8;
            gld_lds16(Bh + off, &Bsh[(size_t)(it * 256 + w * 64) * 8]);
            gld_lds16(Bl + off, &Bsl[(size_t)(it * 256 + w * 64) * 8]);
        }
        __syncthreads();

        #pragma unroll
        for (int ks = 0; ks < 2; ++ks) {
            f16x8 ah[2], al[2];
            #pragma unroll
            for (int mf = 0; mf < 2; ++mf) {
                const int row = wm * 32 + mf * 16 + lr;
                const int kb  = ks * 4 + lk;
                const int o   = row * 64 + ((kb ^ (row & 7)) << 3);
                ah[mf] = *(const f16x8*)&Ash[o];
                al[mf] = *(const f16x8*)&Asl[o];
            }
            #pragma unroll
            for (int nf = 0; nf < 4; ++nf) {
                const int row = wn * 64 + nf * 16 + lr;
                const int kb  = ks * 4 + lk;
                const int o   = row * 64 + ((kb ^ (row & 7)) << 3);
                const f16x8 bh = *(const f16x8*)&Bsh[o];
                const f16x8 bl = *(const f16x8*)&Bsl[o];
                #pragma unroll
                for (int mf = 0; mf < 2; ++mf) {
                    acc0[mf][nf] = __builtin_amdgcn_mfma_f32_16x16x32_f16(
                        ah[mf], bh, acc0[mf][nf], 0, 0, 0);
                    acc1[mf][nf] = __builtin_amdgcn_mfma_f32_16x16x32_f16(
                        ah[mf], bl, acc1[mf][nf], 0, 0, 0);
                    acc1[mf][nf] = __builtin_amdgcn_mfma_f32_16x16x32_f16(
                        al[mf], bh, acc1[mf][nf], 0, 0, 0);
                }
            }
        }
        __syncthreads();
    }

    float bv[4];
    #pragma unroll
    for (int nf = 0; nf < 4; ++nf)
        bv[nf] = bias[n0 + wn * 64 + nf * 16 + lr];
    #pragma unroll
    for (int mf = 0; mf < 2; ++mf)
        #pragma unroll
        for (int nf = 0; nf < 4; ++nf)
            #pragma unroll
            for (int r = 0; r < 4; ++r) {
                const int m = m0 + wm * 32 + mf * 16 + lk * 4 + r;
                const int n = n0 + wn * 64 + nf * 16 + lr;
                float x = acc0[mf][nf][r] + acc1[mf][nf][r] * (1.0f / 2048.0f) + bv[nf];
                x = fmaxf(x, 0.f);
                C[(size_t)m * N + n] = x;
                if (LIMBS) {
                    const f16 h = (f16)x;
                    const f16 lo = (f16)((x - (float)h) * 2048.0f);
                    Ch[(size_t)m * N + n] = __builtin_bit_cast(ushort_t, h);
                    Cl[(size_t)m * N + n] = __builtin_bit_cast(ushort_t, lo);
                }
            }
}

// ---------------------------------------------------------------------------
__global__ __launch_bounds__(256)
void split2_kernel(const float* __restrict__ in, ushort_t* __restrict__ a0,
                   ushort_t* __restrict__ a1, int n4)
{
    for (int i = blockIdx.x * 256 + threadIdx.x; i < n4; i += gridDim.x * 256) {
        const float4 x = ((const float4*)in)[i];
        const float xs[4] = {x.x, x.y, x.z, x.w};
        ushort_t h0[4], h1[4];
        #pragma unroll
        for (int j = 0; j < 4; ++j) {
            const f16 hv = (f16)xs[j];
            const f16 lv = (f16)((xs[j] - (float)hv) * 2048.0f);
            h0[j] = __builtin_bit_cast(ushort_t, hv);
            h1[j] = __builtin_bit_cast(ushort_t, lv);
        }
        *(uint2*)&a0[(size_t)i * 4] = make_uint2(h0[0] | ((unsigned)h0[1] << 16),
                                                 h0[2] | ((unsigned)h0[3] << 16));
        *(uint2*)&a1[(size_t)i * 4] = make_uint2(h1[0] | ((unsigned)h1[1] << 16),
                                                 h1[2] | ((unsigned)h1[3] << 16));
    }
}

// ---------------------------------------------------------------------------
__global__ __launch_bounds__(256)
void tsplit2_kernel(const float* __restrict__ in, ushort_t* __restrict__ t0,
                    ushort_t* __restrict__ t1, int K, int N)
{
    __shared__ float tile[32][33];
    const int t = threadIdx.x;
    const int bk = blockIdx.x * 32, bn = blockIdx.y * 32;
    const int c = t & 31, rb = t >> 5;
    #pragma unroll
    for (int i = 0; i < 4; ++i) {
        const int r = rb + i * 8;
        tile[r][c] = in[(size_t)(bk + r) * N + bn + c];
    }
    __syncthreads();
    #pragma unroll
    for (int i = 0; i < 4; ++i) {
        const int rr = rb + i * 8;
        const float x = tile[c][rr];
        const f16 hv = (f16)x;
        const f16 lv = (f16)((x - (float)hv) * 2048.0f);
        const size_t o = (size_t)(bn + rr) * K + bk + c;
        t0[o] = __builtin_bit_cast(ushort_t, hv);
        t1[o] = __builtin_bit_cast(ushort_t, lv);
    }
}

// ---------------------------------------------------------------------------
__global__ __launch_bounds__(256)
void gemm_trans_kernel(const float* __restrict__ A, const float* __restrict__ Bm,
                       float* __restrict__ C, int M, int KA, int N)
{
    constexpr int BK = 16;
    __shared__ float Asb[BK][64 + 4];
    __shared__ float Bsb[BK][64 + 4];
    const int tid = threadIdx.x;
    const int tx = tid & 15, ty = tid >> 4;
    const int m0 = blockIdx.y * 64, n0 = blockIdx.x * 64;

    float acc[4][4] = {};
    const int lr = tid >> 2, lc = (tid & 3) << 2;
    const int kr = tid >> 4, nc = (tid & 15) << 2;

    for (int k0 = 0; k0 < KA; k0 += BK) {
        const float4 a4 = *reinterpret_cast<const float4*>(A + (size_t)(m0 + lr) * KA + k0 + lc);
        const float4 b4 = *reinterpret_cast<const float4*>(Bm + (size_t)(k0 + kr) * N + n0 + nc);
        Asb[lc + 0][lr] = a4.x; Asb[lc + 1][lr] = a4.y;
        Asb[lc + 2][lr] = a4.z; Asb[lc + 3][lr] = a4.w;
        *reinterpret_cast<float4*>(&Bsb[kr][nc]) = b4;
        __syncthreads();
        #pragma unroll
        for (int kk = 0; kk < BK; ++kk) {
            const float4 av = *reinterpret_cast<const float4*>(&Asb[kk][ty << 2]);
            const float4 bv = *reinterpret_cast<const float4*>(&Bsb[kk][tx << 2]);
            const float a[4] = {av.x, av.y, av.z, av.w};
            const float b[4] = {bv.x, bv.y, bv.z, bv.w};
            #pragma unroll
            for (int i = 0; i < 4; ++i)
                #pragma unroll
                for (int j = 0; j < 4; ++j)
                    acc[i][j] = fmaf(a[i], b[j], acc[i][j]);
        }
        __syncthreads();
    }
    #pragma unroll
    for (int i = 0; i < 4; ++i) {
        const int m = m0 + (ty << 2) + i;
        const int b = m >> 12, s = m & (S_ - 1);
        #pragma unroll
        for (int j = 0; j < 4; ++j) {
            const int n = n0 + (tx << 2) + j;
            C[(size_t)(b * N + n) * S_ + s] = acc[i][j];
        }
    }
}

// ---------------------------------------------------------------------------
__global__ __launch_bounds__(256)
void var_kernel(const float* __restrict__ rmvT, float* __restrict__ hvars)
{
    const int bk = blockIdx.x;
    const float* src = rmvT + (size_t)bk * S_;
    float s1 = 0.f, s2 = 0.f;
    for (int t = threadIdx.x; t < S_; t += 256) {
        const float v = src[t];
        s1 += v; s2 += v * v;
    }
    #pragma unroll
    for (int off = 32; off; off >>= 1) {
        s1 += __shfl_xor(s1, off);
        s2 += __shfl_xor(s2, off);
    }
    __shared__ float r1[4], r2[4];
    const int wave = threadIdx.x >> 6, lane = threadIdx.x & 63;
    if (lane == 0) { r1[wave] = s1; r2[wave] = s2; }
    __syncthreads();
    if (threadIdx.x == 0) {
        const float t1 = r1[0] + r1[1] + r1[2] + r1[3];
        const float t2 = r2[0] + r2[1] + r2[2] + r2[3];
        const float mu = t1 / (float)S_;
        hvars[bk] = t2 / (float)S_ - mu * mu;
    }
}

__global__ void topk_kernel(const float* __restrict__ hvars, int* __restrict__ topidx)
{
    const int b = threadIdx.x;
    if (b >= B_) return;
    float v[KK];
    for (int k = 0; k < KK; ++k) v[k] = hvars[b * KK + k];
    for (int i = 0; i < KH; ++i) {
        int best = 0; float bv = -3.4e38f;
        for (int k = 0; k < KK; ++k)
            if (v[k] > bv) { bv = v[k]; best = k; }
        topidx[b * KH + i] = best;
        v[best] = -3.4e38f;
    }
}

__global__ __launch_bounds__(1024)
void sort_kernel(const float* __restrict__ rmvT, const int* __restrict__ topidx,
                 int* __restrict__ gidx)
{
    const int b = blockIdx.x >> 2;
    const int i = blockIdx.x & 3;
    __shared__ float key[S_];
    __shared__ int   idx[S_];
    const int k = topidx[b * KH + i];
    const float* src = rmvT + (size_t)(b * KK + k) * S_;
    for (int t = threadIdx.x; t < S_; t += 1024) { key[t] = src[t]; idx[t] = t; }
    __syncthreads();
    for (int sz = 2; sz <= S_; sz <<= 1) {
        for (int st = sz >> 1; st > 0; st >>= 1) {
            for (int t = threadIdx.x; t < S_; t += 1024) {
                const int l = t ^ st;
                if (l > t) {
                    const float ka = key[t], kb = key[l];
                    const int   ia = idx[t], ib = idx[l];
                    const bool agtb = (ka > kb) || (ka == kb && ia > ib);
                    const bool up = ((t & sz) == 0);
                    if (up ? agtb : !agtb) {
                        key[t] = kb; key[l] = ka;
                        idx[t] = ib; idx[l] = ia;
                    }
                }
            }
            __syncthreads();
        }
    }
    for (int j = threadIdx.x; j < S_; j += 1024)
        gidx[((b << 12) + j) * KH + i] = (b << 12) + idx[j];
}

// ---------------------------------------------------------------------------
// Fused scores + weighted window sum + residual + LayerNorm.
// XCD-contiguous block swizzle: each XCD gets a contiguous 2048-row chunk so
// the 9-row overlapping v/q2 windows stay resident in its private L2.
// Score arithmetic (dot tree, softmax op order) identical to round-4's
// score_kernel -> bit-identical output.
// ---------------------------------------------------------------------------
__global__ __launch_bounds__(256)
void final_kernel(const float* __restrict__ v, const float* __restrict__ q2,
                  const float* __restrict__ inputs, const float* __restrict__ gamma,
                  const float* __restrict__ beta, float* __restrict__ out)
{
    const int bid = blockIdx.x;
    const int m = ((bid & 7) << 11) | (bid >> 3);   // XCD swizzle (16384 = 8*2048)
    const int s = m & (S_ - 1), b = m >> 12;
    const int tid = threadIdx.x;
    const int wave = tid >> 6, lane = tid & 63;
    __shared__ float sc_s[WW];
    __shared__ float r1[4], r2[4];
    __shared__ float mu_s, rs_s;

    const int jb = (s < (WW - 1) / 2) ? 0 : (s >= S_ - (WW - 1) / 2 ? S_ - WW : s - (WW - 1) / 2);

    // ---- phase 1: 9 window scores (4 waves cover 9 windows) ----
    const float4 qv = *reinterpret_cast<const float4*>(q2 + (size_t)m * DL + (lane << 2));
    const float* kbase = q2 + (size_t)(b * S_ + jb) * DL;
    for (int w = wave; w < WW; w += 4) {
        const float4 kv = *reinterpret_cast<const float4*>(kbase + w * DL + (lane << 2));
        float d = qv.x * kv.x + qv.y * kv.y + qv.z * kv.z + qv.w * kv.w;
        #pragma unroll
        for (int off = 32; off; off >>= 1) d += __shfl_xor(d, off);
        if (lane == 0) sc_s[w] = d * 0.0625f;
    }
    __syncthreads();

    // softmax (redundant per thread; deterministic)
    float mx = sc_s[0];
    #pragma unroll
    for (int w = 1; w < WW; ++w) mx = fmaxf(mx, sc_s[w]);
    float e[WW]; float sum = 0.f;
    #pragma unroll
    for (int w = 0; w < WW; ++w) { e[w] = __expf(sc_s[w] - mx); sum += e[w]; }
    const float inv = 1.f / sum;
    float wgt[WW];
    #pragma unroll
    for (int w = 0; w < WW; ++w) wgt[w] = e[w] * inv;

    // ---- phase 2: weighted window sum + residual + LayerNorm ----
    const float* vb  = v + (size_t)(b * S_ + jb) * DH;
    const float* inp = inputs + (size_t)m * DH;
    float x[4];
    float s1 = 0.f, s2 = 0.f;
    #pragma unroll
    for (int c = 0; c < 4; ++c) {
        const int h = tid + (c << 8);
        float acc = 0.f;
        #pragma unroll
        for (int w = 0; w < WW; ++w) acc = fmaf(wgt[w], vb[w * DH + h], acc);
        acc += inp[h];
        x[c] = acc;
        s1 += acc; s2 += acc * acc;
    }
    #pragma unroll
    for (int off = 32; off; off >>= 1) {
        s1 += __shfl_xor(s1, off);
        s2 += __shfl_xor(s2, off);
    }
    if (lane == 0) { r1[wave] = s1; r2[wave] = s2; }
    __syncthreads();
    if (tid == 0) {
        const float t1 = r1[0] + r1[1] + r1[2] + r1[3];
        const float t2 = r2[0] + r2[1] + r2[2] + r2[3];
        const float mu = t1 / (float)DH;
        mu_s = mu;
        rs_s = rsqrtf(t2 / (float)DH - mu * mu + 0.001f);
    }
    __syncthreads();
    const float mu = mu_s, rs = rs_s;
    #pragma unroll
    for (int c = 0; c < 4; ++c) {
        const int h = tid + (c << 8);
        out[(size_t)m * DH + h] = gamma[h] * (x[c] - mu) * rs + beta[h];
    }
}

// ---------------------------------------------------------------------------
extern "C" void kernel_launch(void* const* d_in, const int* in_sizes, int n_in,
                              void* d_out, int out_size, void* d_ws, size_t ws_size,
                              hipStream_t stream)
{
    (void)in_sizes; (void)n_in; (void)out_size; (void)ws_size;
    const float* inputs = (const float*)d_in[0];
    const float* W1     = (const float*)d_in[1];
    const float* b1     = (const float*)d_in[2];
    const float* RME    = (const float*)d_in[3];
    const float* K2     = (const float*)d_in[4];
    const float* b2     = (const float*)d_in[5];
    const float* Wu     = (const float*)d_in[6];
    const float* bu     = (const float*)d_in[7];
    const float* gamma  = (const float*)d_in[8];
    const float* beta   = (const float*)d_in[9];
    float* out = (float*)d_out;

    char* ws = (char*)d_ws;
    const size_t MB = 1u << 20;
    ushort_t* inh = (ushort_t*)(ws + 0 * MB);      // 32MB
    ushort_t* inl = (ushort_t*)(ws + 32 * MB);     // 32MB
    float*    v   = (float*)   (ws + 0 * MB);      // 64MB (alias, after #1)
    float*    q   = (float*)   (ws + 64 * MB);     // 16MB
    ushort_t* qh  = (ushort_t*)(ws + 80 * MB);     // 8MB
    ushort_t* ql  = (ushort_t*)(ws + 88 * MB);     // 8MB
    float*    q2  = (float*)   (ws + 96 * MB);     // 16MB
    ushort_t* q2h = (ushort_t*)(ws + 112 * MB);    // 8MB
    ushort_t* q2l = (ushort_t*)(ws + 120 * MB);    // 8MB
    float*    rmvT= (float*)   (ws + 128 * MB);    // 4MB
    float*    hvars  = (float*)(ws + 132 * MB);
    int*      topidx = (int*)  (ws + 132 * MB + 4096);
    int*      gidx   = (int*)  (ws + 132 * MB + 8192);   // 256KB
    ushort_t* w1th = (ushort_t*)(ws + 133 * MB);
    ushort_t* w1tl = w1th + (DH * DL);
    ushort_t* k2th = w1tl + (DH * DL);
    ushort_t* k2tl = k2th + (KH * DL * DL);
    ushort_t* wuth = k2tl + (KH * DL * DL);
    ushort_t* wutl = wuth + (DL * DH);

    const int M = B_ * S_;

    // 0a. 2-limb fp16 split of inputs
    split2_kernel<<<dim3(4096), dim3(256), 0, stream>>>(inputs, inh, inl, M * DH / 4);
    // 0b. transpose+split weights
    tsplit2_kernel<<<dim3(DH / 32, DL / 32), dim3(256), 0, stream>>>(W1, w1th, w1tl, DH, DL);
    tsplit2_kernel<<<dim3(KH * DL / 32, DL / 32), dim3(256), 0, stream>>>((const float*)K2, k2th, k2tl, KH * DL, DL);
    tsplit2_kernel<<<dim3(DL / 32, DH / 32), dim3(256), 0, stream>>>(Wu, wuth, wutl, DL, DH);

    // 1. q = relu(inputs @ W1 + b1)
    mfma_gemm2<false, true><<<dim3(DL / 128, M / 64), dim3(256), 0, stream>>>(
        inh, inl, w1th, w1tl, b1, q, qh, ql, nullptr, DH, DL);
    // 2. RMVsT[b][k][s] = (q @ RME)^T  (fp32, key path)
    gemm_trans_kernel<<<dim3(KK / 64, M / 64), dim3(256), 0, stream>>>(q, RME, rmvT, M, DL, KK);
    // 3-5. variance, top-4 heads, stable argsort -> gather table
    var_kernel<<<dim3(B_ * KK), dim3(256), 0, stream>>>(rmvT, hvars);
    topk_kernel<<<dim3(1), dim3(64), 0, stream>>>(hvars, topidx);
    sort_kernel<<<dim3(B_ * KH), dim3(1024), 0, stream>>>(rmvT, topidx, gidx);
    // 6. q2 = relu(gather(q) @ K2 + b2)
    mfma_gemm2<true, true><<<dim3(DL / 128, M / 64), dim3(256), 0, stream>>>(
        qh, ql, k2th, k2tl, b2, q2, q2h, q2l, gidx, KH * DL, DL);
    // 7. v = relu(q2 @ Wu + bu)
    mfma_gemm2<false, false><<<dim3(DH / 128, M / 64), dim3(256), 0, stream>>>(
        q2h, q2l, wuth, wutl, bu, v, nullptr, nullptr, nullptr, DL, DH);
    // 8+9. fused scores + weighted window sum + residual + LayerNorm
    final_kernel<<<dim3(M), dim3(256), 0, stream>>>(v, q2, inputs, gamma, beta, out);
}